// Round 7
// baseline (226.836 us; speedup 1.0000x reference)
//
#include <hip/hip_runtime.h>
#include <hip/hip_bf16.h>
#include <math.h>

#define N_TOK 8192
#define HDIM  1024
#define NE    8
#define TILE  128
#define BK    64
#define KSLAB 16                   // HDIM/BK
#define NGATE (N_TOK / 4)          // gate blocks (4 tokens each)
#define NWTILE (NE * 8 * KSLAB)    // 1024 w-tiler blocks

typedef __attribute__((ext_vector_type(8))) short bf16x8;
typedef __attribute__((ext_vector_type(8))) unsigned short u16x8;
typedef __attribute__((ext_vector_type(4))) float f32x4;
typedef unsigned short u16;

__device__ __forceinline__ u16 f2bf(float f) {
    union { float f; unsigned u; } v; v.f = f;
    unsigned r = v.u + 0x7FFFu + ((v.u >> 16) & 1u);   // round-to-nearest-even
    return (u16)(r >> 16);
}
__device__ __forceinline__ float bf2f(u16 h) {
    union { unsigned u; float f; } v; v.u = (unsigned)h << 16; return v.f;
}

__device__ __forceinline__ void gld_lds16(const void* g, void* lds) {
    __builtin_amdgcn_global_load_lds(
        (const __attribute__((address_space(1))) unsigned int*)g,
        (__attribute__((address_space(3))) unsigned int*)lds,
        16, 0, 0);
}

// tile-slab layout shared by writers and GEMM: slot s in [0,1024):
//   row r = s>>3, chunk c = (s&7)^(r&7)  (chunk = 8 bf16 = 16 B of K)
// slab = 1024 slots = 16 KB; full tile = KSLAB slabs = 256 KB.

// ---- prep: [0,NGATE) gate blocks; [NGATE, NGATE+NWTILE) expert_w tiler blocks ----
__global__ __launch_bounds__(256)
void prep_kernel(const float* __restrict__ w, u16* __restrict__ wbf,
                 const float* __restrict__ x,
                 const float* __restrict__ gate_w,
                 const float* __restrict__ gate_b,
                 int* __restrict__ eids,       // [N_TOK] e0 | e1<<8
                 float2* __restrict__ gatesv)  // [N_TOK] (g0,g1)
{
    int bid = blockIdx.x;
    if (bid >= NGATE) {
        int bid2 = bid - NGATE;                 // = (e*8 + nt)*16 + ks
        int e  = bid2 >> 7;
        int nt = (bid2 >> 4) & 7;
        int ks = bid2 & 15;
        size_t tile = (size_t)bid2 * 8192;      // u16 units (16 KB per slab)
        int tid = threadIdx.x;
#pragma unroll
        for (int j = 0; j < 4; ++j) {
            int s = j * 256 + tid;
            int r = s >> 3;
            int c = (s & 7) ^ (r & 7);
            const float* src = w + ((size_t)e * HDIM + nt * TILE + r) * HDIM + ks * BK + c * 8;
            float4 v0 = ((const float4*)src)[0];
            float4 v1 = ((const float4*)src)[1];
            u16x8 b;
            b[0] = f2bf(v0.x); b[1] = f2bf(v0.y); b[2] = f2bf(v0.z); b[3] = f2bf(v0.w);
            b[4] = f2bf(v1.x); b[5] = f2bf(v1.y); b[6] = f2bf(v1.z); b[7] = f2bf(v1.w);
            *(u16x8*)(wbf + tile + (size_t)s * 8) = b;
        }
        return;
    }
    int wave = threadIdx.x >> 6, lane = threadIdx.x & 63;
    int t = bid * 4 + wave;
    const float4* xt = (const float4*)(x + (size_t)t * HDIM);

    float acc[NE];
#pragma unroll
    for (int e = 0; e < NE; ++e) acc[e] = 0.f;

#pragma unroll
    for (int i = 0; i < 4; ++i) {
        int f = i * 64 + lane;
        float4 v = xt[f];
#pragma unroll
        for (int e = 0; e < NE; ++e) {
            float4 wv = ((const float4*)(gate_w + e * HDIM))[f];
            acc[e] += v.x * wv.x + v.y * wv.y + v.z * wv.z + v.w * wv.w;
        }
    }
#pragma unroll
    for (int e = 0; e < NE; ++e)
        for (int off = 32; off > 0; off >>= 1)
            acc[e] += __shfl_down(acc[e], off);

    if (lane == 0) {
        float logit[NE];
        float mx = -1e30f;
#pragma unroll
        for (int e = 0; e < NE; ++e) {
            logit[e] = acc[e] + gate_b[e];
            mx = fmaxf(mx, logit[e]);
        }
        float p[NE], s = 0.f;
#pragma unroll
        for (int e = 0; e < NE; ++e) { p[e] = expf(logit[e] - mx); s += p[e]; }
        float inv = 1.f / s;
        int i0 = 0;
#pragma unroll
        for (int e = 1; e < NE; ++e) if (logit[e] > logit[i0]) i0 = e;
        int i1 = (i0 == 0) ? 1 : 0;
#pragma unroll
        for (int e = 0; e < NE; ++e) if (e != i0 && logit[e] > logit[i1]) i1 = e;

        eids[t]   = i0 | (i1 << 8);
        gatesv[t] = make_float2(p[i0] * inv, p[i1] * inv);
    }
}

// ---- compact: single block, hist+rank+scatter + padded tile prefix ----
__global__ __launch_bounds__(1024)
void compact_kernel(const int* __restrict__ eids,
                    const float2* __restrict__ gatesv,
                    int* __restrict__ tok_list, float* __restrict__ gate_list,
                    int* __restrict__ counts, int* __restrict__ tbase)
{
    __shared__ int lh[16][NE];
    __shared__ int lbase[16][NE];
    int tid = threadIdx.x;
    if (tid < 16 * NE) ((int*)lh)[tid] = 0;
    __syncthreads();
    int bucket = tid & 15;

    int e0v[8], e1v[8], r0v[8], r1v[8];
    float2 gv[8];
#pragma unroll
    for (int it = 0; it < 8; ++it) {
        int t = it * 1024 + tid;
        int ee = eids[t];
        e0v[it] = ee & 255; e1v[it] = (ee >> 8) & 255;
        gv[it] = gatesv[t];
        r0v[it] = atomicAdd(&lh[bucket][e0v[it]], 1);
        r1v[it] = atomicAdd(&lh[bucket][e1v[it]], 1);
    }
    __syncthreads();
    if (tid < NE) {
        int run = 0;
        for (int b = 0; b < 16; ++b) { lbase[b][tid] = run; run += lh[b][tid]; }
        counts[tid] = run;
    }
    __syncthreads();
    if (tid == 0) {
        int tb = 0;
        for (int e = 0; e < NE; ++e) { tbase[e] = tb; tb += (counts[e] + TILE - 1) / TILE; }
    }
#pragma unroll
    for (int it = 0; it < 8; ++it) {
        int t = it * 1024 + tid;
        int p0 = lbase[bucket][e0v[it]] + r0v[it];
        tok_list[e0v[it] * N_TOK + p0]  = t * 2;        // token*2 + slot
        gate_list[e0v[it] * N_TOK + p0] = gv[it].x;
        int p1 = lbase[bucket][e1v[it]] + r1v[it];
        tok_list[e1v[it] * N_TOK + p1]  = t * 2 + 1;
        gate_list[e1v[it] * N_TOK + p1] = gv[it].y;
    }
}

// ---- atile: gather tokens ONCE per m-tile, convert fp32->bf16, write tile-slab layout ----
__global__ __launch_bounds__(256)
void atile_kernel(const float* __restrict__ x,
                  const int* __restrict__ tok_list,
                  const int* __restrict__ counts,
                  const int* __restrict__ tbase,
                  u16* __restrict__ xg)
{
    int e   = blockIdx.y;
    int cnt = counts[e];
    int mt  = blockIdx.x >> 4;
    int ks  = blockIdx.x & 15;
    int m0  = mt << 7;
    if (m0 >= cnt) return;
    size_t tile = ((size_t)(tbase[e] + mt) * KSLAB + ks) * 8192;
    int tid = threadIdx.x;
#pragma unroll
    for (int j = 0; j < 4; ++j) {
        int s = j * 256 + tid;
        int r = s >> 3;
        int c = (s & 7) ^ (r & 7);
        int tr = m0 + r; if (tr > cnt - 1) tr = cnt - 1;   // dup rows never read back
        int tok = tok_list[e * N_TOK + tr] >> 1;
        const float* src = x + (size_t)tok * HDIM + ks * BK + c * 8;
        float4 v0 = ((const float4*)src)[0];
        float4 v1 = ((const float4*)src)[1];
        u16x8 b;
        b[0] = f2bf(v0.x); b[1] = f2bf(v0.y); b[2] = f2bf(v0.z); b[3] = f2bf(v0.w);
        b[4] = f2bf(v1.x); b[5] = f2bf(v1.y); b[6] = f2bf(v1.z); b[7] = f2bf(v1.w);
        *(u16x8*)(xg + tile + (size_t)s * 8) = b;
    }
}

// ---- grouped per-expert GEMM: streaming pre-tiled staging + XCD remap ----
// 1-D grid of 4096: grp = bid>>6, e = grp>>3, m_tile = (grp&7)*8 + (bid&7),
// n_tile = (bid>>3)&7. XCD = bid%8 => one m-tile's A slabs pinned per XCD L2.
// Each global_load_lds reads 1 KiB fully contiguous (slot order == file order).
__global__ __launch_bounds__(256)
void moe_gemm_kernel(const u16* __restrict__ xg,
                     const u16* __restrict__ wbf,
                     const float* __restrict__ expert_b,
                     const int* __restrict__ counts,
                     const int* __restrict__ tbase,
                     const int* __restrict__ tok_list,
                     const float* __restrict__ gate_list,
                     float* __restrict__ out,     // slot0 partials (fp32)
                     u16* __restrict__ part1)     // slot1 partials (bf16)
{
    int bid = blockIdx.x;
    int grp = bid >> 6;
    int e   = grp >> 3;
    int cnt = counts[e];
    int m0  = (((grp & 7) << 3) | (bid & 7)) * TILE;
    if (m0 >= cnt) return;
    int nt  = (bid >> 3) & 7;
    int n0  = nt * TILE;

    __shared__ __align__(16) u16 As[1024 * 8];   // 16 KB
    __shared__ __align__(16) u16 Bs[1024 * 8];   // 16 KB

    int tid = threadIdx.x;
    int w = tid >> 6, l = tid & 63;
    int s0 = w * 64 + l;                          // this lane's slot in instr 0

    const u16* aLane = xg  + ((size_t)(tbase[e] + (m0 >> 7)) * KSLAB) * 8192 + (size_t)s0 * 8;
    const u16* bLane = wbf + ((size_t)(e * 8 + nt) * KSLAB) * 8192 + (size_t)s0 * 8;

    int wm = (w >> 1) * 64, wn = (w & 1) * 64;
    int lrow = l & 15, quad = l >> 4;
    int cxbase = lrow & 7;

    f32x4 acc[4][4];
#pragma unroll
    for (int mi = 0; mi < 4; ++mi)
#pragma unroll
        for (int ni = 0; ni < 4; ++ni)
            acc[mi][ni] = (f32x4){0.f, 0.f, 0.f, 0.f};

    for (int ks = 0; ks < KSLAB; ++ks) {
        const u16* aS = aLane + (size_t)ks * 8192;
        const u16* bS = bLane + (size_t)ks * 8192;
#pragma unroll
        for (int j = 0; j < 4; ++j) {
            gld_lds16(aS + j * 2048, As + (j * 256 + w * 64) * 8);
            gld_lds16(bS + j * 2048, Bs + (j * 256 + w * 64) * 8);
        }
        __syncthreads();

#pragma unroll
        for (int t2 = 0; t2 < 2; ++t2) {
            int cx = (t2 * 4 + quad) ^ cxbase;
            bf16x8 af[4], bfr[4];
#pragma unroll
            for (int i = 0; i < 4; ++i) {
                int ra = wm + i * 16 + lrow;
                int rb = wn + i * 16 + lrow;
                af[i]  = *(const bf16x8*)(As + (ra * 8 + cx) * 8);
                bfr[i] = *(const bf16x8*)(Bs + (rb * 8 + cx) * 8);
            }
#pragma unroll
            for (int mi = 0; mi < 4; ++mi)
#pragma unroll
                for (int ni = 0; ni < 4; ++ni)
                    acc[mi][ni] = __builtin_amdgcn_mfma_f32_16x16x32_bf16(
                        af[mi], bfr[ni], acc[mi][ni], 0, 0, 0);
        }
        __syncthreads();
    }

    // epilogue: bias + gate; slot0 -> fp32 out, slot1 -> bf16 part1
#pragma unroll
    for (int mi = 0; mi < 4; ++mi) {
#pragma unroll
        for (int rr = 0; rr < 4; ++rr) {
            int listRow = m0 + wm + mi * 16 + quad * 4 + rr;
            if (listRow < cnt) {
                int   lst = tok_list[e * N_TOK + listRow];
                float g   = gate_list[e * N_TOK + listRow];
                size_t rowOff = (size_t)(lst >> 1) * HDIM;
                if (lst & 1) {
#pragma unroll
                    for (int ni = 0; ni < 4; ++ni) {
                        int col = n0 + wn + ni * 16 + lrow;
                        part1[rowOff + col] =
                            f2bf((acc[mi][ni][rr] + expert_b[e * HDIM + col]) * g);
                    }
                } else {
#pragma unroll
                    for (int ni = 0; ni < 4; ++ni) {
                        int col = n0 + wn + ni * 16 + lrow;
                        out[rowOff + col] =
                            (acc[mi][ni][rr] + expert_b[e * HDIM + col]) * g;
                    }
                }
            }
        }
    }
}

// ---- combine: out += upconvert(part1) ----
__global__ __launch_bounds__(256)
void combine_kernel(float* __restrict__ out, const u16* __restrict__ part1) {
    size_t i = (size_t)blockIdx.x * 256 + threadIdx.x;
    float4 a = ((const float4*)out)[i];
    ushort4 b = ((const ushort4*)part1)[i];
    a.x += bf2f(b.x); a.y += bf2f(b.y); a.z += bf2f(b.z); a.w += bf2f(b.w);
    ((float4*)out)[i] = a;
}

extern "C" void kernel_launch(void* const* d_in, const int* in_sizes, int n_in,
                              void* d_out, int out_size, void* d_ws, size_t ws_size,
                              hipStream_t stream)
{
    const float* x        = (const float*)d_in[0];
    const float* gate_w   = (const float*)d_in[1];
    const float* gate_b   = (const float*)d_in[2];
    const float* expert_w = (const float*)d_in[3];
    const float* expert_b = (const float*)d_in[4];
    float* out = (float*)d_out;

    char* ws = (char*)d_ws;
    int*    eids      = (int*)(ws);                          // 32 KB
    float2* gatesv    = (float2*)(ws + (64 << 10));          // 64 KB
    int*    counts    = (int*)(ws + (132 << 10));            // 32 B
    int*    tbase     = (int*)(ws + (132 << 10) + 64);       // 36 B
    int*    tok_list  = (int*)(ws + (136 << 10));            // 256 KB
    float*  gate_list = (float*)(ws + (136 << 10) + NE * N_TOK * 4); // 256 KB
    u16*    xg        = (u16*)(ws + (1 << 20));              // <= 33.8 MB (135 tiles max)
    u16*    wbf       = (u16*)(ws + (36u << 20));            // 16 MB
    u16*    part1     = (u16*)(ws + (52u << 20));            // 16 MB -> ends at 68 MB

    prep_kernel<<<NGATE + NWTILE, 256, 0, stream>>>(expert_w, wbf, x, gate_w, gate_b,
                                                    eids, gatesv);
    compact_kernel<<<1, 1024, 0, stream>>>(eids, gatesv, tok_list, gate_list,
                                           counts, tbase);
    atile_kernel<<<dim3(64 * KSLAB, NE), 256, 0, stream>>>(x, tok_list, counts, tbase, xg);

    moe_gemm_kernel<<<4096, 256, 0, stream>>>(xg, wbf, expert_b,
                                              counts, tbase, tok_list, gate_list,
                                              out, part1);

    combine_kernel<<<N_TOK * HDIM / 4 / 256, 256, 0, stream>>>(out, part1);
}